// Round 1
// baseline (1496.862 us; speedup 1.0000x reference)
//
#include <hip/hip_runtime.h>
#include <hip/hip_bf16.h>

#define NB    65536
#define NT    5
#define NOBS  128
#define NACT  32
#define NH    64

__device__ __forceinline__ float sigf(float x) { return 1.0f / (1.0f + __expf(-x)); }
__device__ __forceinline__ float tanh_fast(float x) { return 1.0f - 2.0f / (__expf(2.0f * x) + 1.0f); }

// ---------------- K0: transpose LSTM kernels [128,256] -> [256,128] ----------
__global__ __launch_bounds__(256) void k0_transpose(
    const float* __restrict__ fk, const float* __restrict__ bk,
    float* __restrict__ fkT, float* __restrict__ bkT) {
  int i = blockIdx.x * 256 + threadIdx.x;   // 0..32767
  int k = i >> 8;                           // 0..127
  int g = i & 255;                          // 0..255
  float a = fk[i];
  float b = bk[i];
  fkT[g * 128 + k] = a;
  bkT[g * 128 + k] = b;
}

// ---------------- K1: fused MLP (LN0 -> W1 -> LN1/relu -> concat -> W2 -> LN2/relu)
// one wave handles 16 rows; lane = output column for the GEMMs.
__global__ __launch_bounds__(256) void k1_mlp(
    const float* __restrict__ ud, const float* __restrict__ action,
    const float* __restrict__ ln0g, const float* __restrict__ ln0b,
    const float* __restrict__ W1, const float* __restrict__ b1,
    const float* __restrict__ ln1g, const float* __restrict__ ln1b,
    const float* __restrict__ W2, const float* __restrict__ b2,
    const float* __restrict__ ln2g, const float* __restrict__ ln2b,
    float* __restrict__ hin) {
  const int wave = threadIdx.x >> 6;
  const int lane = threadIdx.x & 63;
  const int base = (blockIdx.x * 4 + wave) * 16;   // first row of this wave

  __shared__ __align__(16) float xs[4][16][128];   // 32 KB

  // ---- load ud rows (2 elements per lane per row) ----
  float v0[16], v1[16];
#pragma unroll
  for (int r = 0; r < 16; ++r) {
    v0[r] = ud[(base + r) * NOBS + lane];
    v1[r] = ud[(base + r) * NOBS + 64 + lane];
  }

  const float g0l = ln0g[lane], g0h = ln0g[64 + lane];
  const float c0l = ln0b[lane], c0h = ln0b[64 + lane];

  // ---- LN0 per row (butterfly over 64 lanes), write normalized to LDS ----
#pragma unroll
  for (int r = 0; r < 16; ++r) {
    float s = v0[r] + v1[r];
    float q = v0[r] * v0[r] + v1[r] * v1[r];
#pragma unroll
    for (int off = 32; off; off >>= 1) {
      s += __shfl_xor(s, off, 64);
      q += __shfl_xor(q, off, 64);
    }
    float m = s * (1.0f / 128.0f);
    float var = q * (1.0f / 128.0f) - m * m;
    float inv = rsqrtf(var + 1e-12f);
    xs[wave][r][lane]      = (v0[r] - m) * inv * g0l + c0l;
    xs[wave][r][64 + lane] = (v1[r] - m) * inv * g0h + c0h;
  }
  __syncthreads();

  // ---- GEMM1: [16,128] @ [128,64] ----
  float acc[16];
  {
    const float bias = b1[lane];
#pragma unroll
    for (int r = 0; r < 16; ++r) acc[r] = bias;
    for (int k = 0; k < 128; k += 4) {
      float w0 = W1[(k + 0) * 64 + lane];
      float w1 = W1[(k + 1) * 64 + lane];
      float w2 = W1[(k + 2) * 64 + lane];
      float w3 = W1[(k + 3) * 64 + lane];
#pragma unroll
      for (int r = 0; r < 16; ++r) {
        const float4 x4 = *(const float4*)&xs[wave][r][k];
        acc[r] = fmaf(x4.x, w0, acc[r]);
        acc[r] = fmaf(x4.y, w1, acc[r]);
        acc[r] = fmaf(x4.z, w2, acc[r]);
        acc[r] = fmaf(x4.w, w3, acc[r]);
      }
    }
  }

  // ---- LN1 over 64 cols + relu ----
  float x1v[16];
  {
    const float g1l = ln1g[lane], c1l = ln1b[lane];
#pragma unroll
    for (int r = 0; r < 16; ++r) {
      float s = acc[r];
      float q = acc[r] * acc[r];
#pragma unroll
      for (int off = 32; off; off >>= 1) {
        s += __shfl_xor(s, off, 64);
        q += __shfl_xor(q, off, 64);
      }
      float m = s * (1.0f / 64.0f);
      float var = q * (1.0f / 64.0f) - m * m;
      float inv = rsqrtf(var + 1e-12f);
      float xv = (acc[r] - m) * inv * g1l + c1l;
      x1v[r] = fmaxf(xv, 0.0f);
    }
  }
  __syncthreads();   // GEMM1 reads done; xs region will be overwritten

  // ---- build xcat = [x1 (64) | action (32)] in xs ----
#pragma unroll
  for (int r = 0; r < 16; ++r) xs[wave][r][lane] = x1v[r];
#pragma unroll
  for (int i = 0; i < 8; ++i) {
    int e = i * 64 + lane;        // 0..511, contiguous over 16 rows x 32
    int r = e >> 5;
    int j = e & 31;
    xs[wave][r][64 + j] = action[base * NACT + e];
  }
  __syncthreads();

  // ---- GEMM2: [16,96] @ [96,64] ----
  float acc2[16];
  {
    const float bias = b2[lane];
#pragma unroll
    for (int r = 0; r < 16; ++r) acc2[r] = bias;
    for (int k = 0; k < 96; k += 4) {
      float w0 = W2[(k + 0) * 64 + lane];
      float w1 = W2[(k + 1) * 64 + lane];
      float w2 = W2[(k + 2) * 64 + lane];
      float w3 = W2[(k + 3) * 64 + lane];
#pragma unroll
      for (int r = 0; r < 16; ++r) {
        const float4 x4 = *(const float4*)&xs[wave][r][k];
        acc2[r] = fmaf(x4.x, w0, acc2[r]);
        acc2[r] = fmaf(x4.y, w1, acc2[r]);
        acc2[r] = fmaf(x4.z, w2, acc2[r]);
        acc2[r] = fmaf(x4.w, w3, acc2[r]);
      }
    }
  }

  // ---- LN2 + relu + store ----
  {
    const float g2l = ln2g[lane], c2l = ln2b[lane];
#pragma unroll
    for (int r = 0; r < 16; ++r) {
      float s = acc2[r];
      float q = acc2[r] * acc2[r];
#pragma unroll
      for (int off = 32; off; off >>= 1) {
        s += __shfl_xor(s, off, 64);
        q += __shfl_xor(q, off, 64);
      }
      float m = s * (1.0f / 64.0f);
      float var = q * (1.0f / 64.0f) - m * m;
      float inv = rsqrtf(var + 1e-12f);
      float xv = (acc2[r] - m) * inv * g2l + c2l;
      hin[(base + r) * NH + lane] = fmaxf(xv, 0.0f);
    }
  }
}

// ---------------- K2: bidirectional LSTM with sequence lengths --------------
// one wave handles 16 batches; lane = hidden unit (holds gates i,j,f,o of unit `lane`).
__global__ __launch_bounds__(256) void k2_lstm(
    const float* __restrict__ hin,
    const float* __restrict__ fkT, const float* __restrict__ fwb,
    const float* __restrict__ bkT, const float* __restrict__ bwb,
    const int* __restrict__ au,
    float* __restrict__ fwout, float* __restrict__ bwout) {
  const int wave = threadIdx.x >> 6;
  const int lane = threadIdx.x & 63;
  const int batch0 = (blockIdx.x * 4 + wave) * 16;

  __shared__ __align__(16) float xh[4][16][128];   // 32 KB

  int aur[16];
#pragma unroll
  for (int b = 0; b < 16; ++b) aur[b] = au[batch0 + b];

  for (int dir = 0; dir < 2; ++dir) {
    const float* kT   = dir ? bkT : fkT;
    const float* bias = dir ? bwb : fwb;
    float* out        = dir ? bwout : fwout;

    const float bi = bias[lane];
    const float bj = bias[64 + lane];
    const float bf = bias[128 + lane];
    const float bo = bias[192 + lane];

    float c[16], h[16];
#pragma unroll
    for (int b = 0; b < 16; ++b) { c[b] = 0.0f; h[b] = 0.0f; }

    for (int t = 0; t < NT; ++t) {
      // stage xh = [x_src | h]
#pragma unroll
      for (int b = 0; b < 16; ++b) {
        int src = t;
        if (dir) src = (t < aur[b]) ? (aur[b] - 1 - t) : t;
        xh[wave][b][lane]      = hin[((batch0 + b) * NT + src) * NH + lane];
        xh[wave][b][64 + lane] = h[b];
      }
      __syncthreads();

      float ai[16], aj[16], af[16], ao[16];
#pragma unroll
      for (int b = 0; b < 16; ++b) { ai[b] = bi; aj[b] = bj; af[b] = bf; ao[b] = bo; }

      for (int k = 0; k < 128; k += 4) {
        const float4 wi = *(const float4*)&kT[(lane) * 128 + k];
        const float4 wj = *(const float4*)&kT[(64 + lane) * 128 + k];
        const float4 wf = *(const float4*)&kT[(128 + lane) * 128 + k];
        const float4 wo = *(const float4*)&kT[(192 + lane) * 128 + k];
#pragma unroll
        for (int b = 0; b < 16; ++b) {
          const float4 x4 = *(const float4*)&xh[wave][b][k];
          ai[b] = fmaf(x4.x, wi.x, ai[b]); ai[b] = fmaf(x4.y, wi.y, ai[b]);
          ai[b] = fmaf(x4.z, wi.z, ai[b]); ai[b] = fmaf(x4.w, wi.w, ai[b]);
          aj[b] = fmaf(x4.x, wj.x, aj[b]); aj[b] = fmaf(x4.y, wj.y, aj[b]);
          aj[b] = fmaf(x4.z, wj.z, aj[b]); aj[b] = fmaf(x4.w, wj.w, aj[b]);
          af[b] = fmaf(x4.x, wf.x, af[b]); af[b] = fmaf(x4.y, wf.y, af[b]);
          af[b] = fmaf(x4.z, wf.z, af[b]); af[b] = fmaf(x4.w, wf.w, af[b]);
          ao[b] = fmaf(x4.x, wo.x, ao[b]); ao[b] = fmaf(x4.y, wo.y, ao[b]);
          ao[b] = fmaf(x4.z, wo.z, ao[b]); ao[b] = fmaf(x4.w, wo.w, ao[b]);
        }
      }
      __syncthreads();   // xh reads done before next step's staging

      // nonlinearity + state update + masked output
#pragma unroll
      for (int b = 0; b < 16; ++b) {
        float ig = sigf(ai[b]);
        float jg = tanh_fast(aj[b]);
        float fg = sigf(af[b] + 1.0f);   // forget bias
        float og = sigf(ao[b]);
        float nc = fg * c[b] + ig * jg;
        float nh = og * tanh_fast(nc);
        bool valid = t < aur[b];
        c[b] = valid ? nc : c[b];
        float outv = valid ? nh : 0.0f;
        h[b] = valid ? nh : h[b];
        int pos = t;
        if (dir) pos = (t < aur[b]) ? (aur[b] - 1 - t) : t;
        out[((batch0 + b) * NT + pos) * NH + lane] = outv;
      }
    }
    __syncthreads();
  }
}

// ---------------- K3: final LN over (T,2H) + relu + conv dot + masked sum ----
// one wave per batch
__global__ __launch_bounds__(256) void k3_final(
    const float* __restrict__ fwout, const float* __restrict__ bwout,
    const float* __restrict__ ln3g, const float* __restrict__ ln3b,
    const float* __restrict__ conv_w, const float* __restrict__ conv_b,
    const float* __restrict__ mask, float* __restrict__ out) {
  const int wave = threadIdx.x >> 6;
  const int lane = threadIdx.x & 63;
  const int b = blockIdx.x * 4 + wave;

  float f[NT], w[NT];
#pragma unroll
  for (int t = 0; t < NT; ++t) {
    f[t] = fwout[(b * NT + t) * NH + lane];
    w[t] = bwout[(b * NT + t) * NH + lane];
  }
  float s = 0.0f, q = 0.0f;
#pragma unroll
  for (int t = 0; t < NT; ++t) {
    s += f[t] + w[t];
    q += f[t] * f[t] + w[t] * w[t];
  }
#pragma unroll
  for (int off = 32; off; off >>= 1) {
    s += __shfl_xor(s, off, 64);
    q += __shfl_xor(q, off, 64);
  }
  float m = s * (1.0f / 640.0f);
  float var = q * (1.0f / 640.0f) - m * m;
  float inv = rsqrtf(var + 1e-12f);

  const float gl = ln3g[lane], gh = ln3g[64 + lane];
  const float bl = ln3b[lane], bh = ln3b[64 + lane];
  const float cwl = conv_w[lane], cwh = conv_w[64 + lane];
  const float cb = conv_b[0];

  float Q = 0.0f;
#pragma unroll
  for (int t = 0; t < NT; ++t) {
    float xf = fmaxf((f[t] - m) * inv * gl + bl, 0.0f);
    float xb = fmaxf((w[t] - m) * inv * gh + bh, 0.0f);
    float p = xf * cwl + xb * cwh;
#pragma unroll
    for (int off = 32; off; off >>= 1) p += __shfl_xor(p, off, 64);
    float qv = p + cb;
    Q += qv * mask[b * NT + t];
  }
  if (lane == 0) out[b] = Q;
}

extern "C" void kernel_launch(void* const* d_in, const int* in_sizes, int n_in,
                              void* d_out, int out_size, void* d_ws, size_t ws_size,
                              hipStream_t stream) {
  const float* ud     = (const float*)d_in[0];
  const float* action = (const float*)d_in[1];
  const float* mask   = (const float*)d_in[2];
  const float* ln0g   = (const float*)d_in[3];
  const float* ln0b   = (const float*)d_in[4];
  const float* W1     = (const float*)d_in[5];
  const float* b1     = (const float*)d_in[6];
  const float* ln1g   = (const float*)d_in[7];
  const float* ln1b   = (const float*)d_in[8];
  const float* W2     = (const float*)d_in[9];
  const float* b2     = (const float*)d_in[10];
  const float* ln2g   = (const float*)d_in[11];
  const float* ln2b   = (const float*)d_in[12];
  const float* fwk    = (const float*)d_in[13];
  const float* fwb    = (const float*)d_in[14];
  const float* bwk    = (const float*)d_in[15];
  const float* bwb    = (const float*)d_in[16];
  const float* ln3g   = (const float*)d_in[17];
  const float* ln3b   = (const float*)d_in[18];
  const float* conv_w = (const float*)d_in[19];
  const float* conv_b = (const float*)d_in[20];
  const int*   au     = (const int*)d_in[21];

  float* wsf = (float*)d_ws;
  const size_t n_hin = (size_t)NB * NT * NH;          // 20,971,520
  float* hin   = wsf;
  float* fwout = wsf + n_hin;
  float* bwout = wsf + 2 * n_hin;
  float* fkT   = wsf + 3 * n_hin;
  float* bkT   = fkT + 128 * 256;

  float* outf = (float*)d_out;

  k0_transpose<<<128, 256, 0, stream>>>(fwk, bwk, fkT, bkT);
  k1_mlp<<<(NB * NT) / 64, 256, 0, stream>>>(ud, action, ln0g, ln0b, W1, b1,
                                             ln1g, ln1b, W2, b2, ln2g, ln2b, hin);
  k2_lstm<<<NB / 64, 256, 0, stream>>>(hin, fkT, fwb, bkT, bwb, au, fwout, bwout);
  k3_final<<<NB / 4, 256, 0, stream>>>(fwout, bwout, ln3g, ln3b, conv_w, conv_b,
                                       mask, outf);
}

// Round 3
// 691.422 us; speedup vs baseline: 2.1649x; 2.1649x over previous
//
#include <hip/hip_runtime.h>
#include <hip/hip_bf16.h>

#define NB    65536
#define NT    5
#define NOBS  128
#define NACT  32
#define NH    64

typedef __attribute__((ext_vector_type(8))) short bf16x8;
typedef __attribute__((ext_vector_type(4))) float f32x4;

__device__ __forceinline__ float sigf(float x) { return 1.0f / (1.0f + __expf(-x)); }
__device__ __forceinline__ float tanh_fast(float x) { return 1.0f - 2.0f / (__expf(2.0f * x) + 1.0f); }

__device__ __forceinline__ unsigned short f2b(float x) {
  __hip_bfloat16 h = __float2bfloat16(x);
  return *(unsigned short*)&h;
}
__device__ __forceinline__ float b2f(unsigned short u) {
  __hip_bfloat16 h = *(__hip_bfloat16*)&u;
  return __bfloat162float(h);
}

// ---------------- K0: transpose + bf16-cast LSTM kernels [128,256] -> [256,128] bf16
// Each thread writes one full aligned 32-bit word (two adjacent k for one column g):
// no 32-bit word of the output is ever written by two different workgroups
// (cross-XCD L2s may track dirty state at dword granularity).
__global__ __launch_bounds__(256) void k0_transpose(
    const float* __restrict__ fk, const float* __restrict__ bk,
    unsigned int* __restrict__ fkT, unsigned int* __restrict__ bkT) {
  const int g  = threadIdx.x;          // 0..255 column (gate-unit)
  const int k0 = blockIdx.x * 2;       // 0..126 even row
  // input is [k][g] row-major
  unsigned int flo = f2b(fk[(k0 + 0) * 256 + g]);
  unsigned int fhi = f2b(fk[(k0 + 1) * 256 + g]);
  unsigned int blo = f2b(bk[(k0 + 0) * 256 + g]);
  unsigned int bhi = f2b(bk[(k0 + 1) * 256 + g]);
  // output row-major [g][k], dword index = (g*128 + k0)/2
  fkT[g * 64 + blockIdx.x] = flo | (fhi << 16);
  bkT[g * 64 + blockIdx.x] = blo | (bhi << 16);
}

// ---------------- K1: fused MLP (LN0 -> W1 -> LN1/relu -> concat -> W2 -> LN2/relu)
// one wave handles 16 rows; lane = output column for the GEMMs. Output hin in bf16.
__global__ __launch_bounds__(256) void k1_mlp(
    const float* __restrict__ ud, const float* __restrict__ action,
    const float* __restrict__ ln0g, const float* __restrict__ ln0b,
    const float* __restrict__ W1, const float* __restrict__ b1,
    const float* __restrict__ ln1g, const float* __restrict__ ln1b,
    const float* __restrict__ W2, const float* __restrict__ b2,
    const float* __restrict__ ln2g, const float* __restrict__ ln2b,
    unsigned short* __restrict__ hin) {
  const int wave = threadIdx.x >> 6;
  const int lane = threadIdx.x & 63;
  const int base = (blockIdx.x * 4 + wave) * 16;

  __shared__ __align__(16) float xs[4][16][128];   // 32 KB

  float v0[16], v1[16];
#pragma unroll
  for (int r = 0; r < 16; ++r) {
    v0[r] = ud[(base + r) * NOBS + lane];
    v1[r] = ud[(base + r) * NOBS + 64 + lane];
  }

  const float g0l = ln0g[lane], g0h = ln0g[64 + lane];
  const float c0l = ln0b[lane], c0h = ln0b[64 + lane];

#pragma unroll
  for (int r = 0; r < 16; ++r) {
    float s = v0[r] + v1[r];
    float q = v0[r] * v0[r] + v1[r] * v1[r];
#pragma unroll
    for (int off = 32; off; off >>= 1) {
      s += __shfl_xor(s, off, 64);
      q += __shfl_xor(q, off, 64);
    }
    float m = s * (1.0f / 128.0f);
    float var = q * (1.0f / 128.0f) - m * m;
    float inv = rsqrtf(var + 1e-12f);
    xs[wave][r][lane]      = (v0[r] - m) * inv * g0l + c0l;
    xs[wave][r][64 + lane] = (v1[r] - m) * inv * g0h + c0h;
  }
  __syncthreads();

  float acc[16];
  {
    const float bias = b1[lane];
#pragma unroll
    for (int r = 0; r < 16; ++r) acc[r] = bias;
    for (int k = 0; k < 128; k += 4) {
      float w0 = W1[(k + 0) * 64 + lane];
      float w1 = W1[(k + 1) * 64 + lane];
      float w2 = W1[(k + 2) * 64 + lane];
      float w3 = W1[(k + 3) * 64 + lane];
#pragma unroll
      for (int r = 0; r < 16; ++r) {
        const float4 x4 = *(const float4*)&xs[wave][r][k];
        acc[r] = fmaf(x4.x, w0, acc[r]);
        acc[r] = fmaf(x4.y, w1, acc[r]);
        acc[r] = fmaf(x4.z, w2, acc[r]);
        acc[r] = fmaf(x4.w, w3, acc[r]);
      }
    }
  }

  float x1v[16];
  {
    const float g1l = ln1g[lane], c1l = ln1b[lane];
#pragma unroll
    for (int r = 0; r < 16; ++r) {
      float s = acc[r];
      float q = acc[r] * acc[r];
#pragma unroll
      for (int off = 32; off; off >>= 1) {
        s += __shfl_xor(s, off, 64);
        q += __shfl_xor(q, off, 64);
      }
      float m = s * (1.0f / 64.0f);
      float var = q * (1.0f / 64.0f) - m * m;
      float inv = rsqrtf(var + 1e-12f);
      float xv = (acc[r] - m) * inv * g1l + c1l;
      x1v[r] = fmaxf(xv, 0.0f);
    }
  }
  __syncthreads();

#pragma unroll
  for (int r = 0; r < 16; ++r) xs[wave][r][lane] = x1v[r];
#pragma unroll
  for (int i = 0; i < 8; ++i) {
    int e = i * 64 + lane;
    int r = e >> 5;
    int j = e & 31;
    xs[wave][r][64 + j] = action[base * NACT + e];
  }
  __syncthreads();

  float acc2[16];
  {
    const float bias = b2[lane];
#pragma unroll
    for (int r = 0; r < 16; ++r) acc2[r] = bias;
    for (int k = 0; k < 96; k += 4) {
      float w0 = W2[(k + 0) * 64 + lane];
      float w1 = W2[(k + 1) * 64 + lane];
      float w2 = W2[(k + 2) * 64 + lane];
      float w3 = W2[(k + 3) * 64 + lane];
#pragma unroll
      for (int r = 0; r < 16; ++r) {
        const float4 x4 = *(const float4*)&xs[wave][r][k];
        acc2[r] = fmaf(x4.x, w0, acc2[r]);
        acc2[r] = fmaf(x4.y, w1, acc2[r]);
        acc2[r] = fmaf(x4.z, w2, acc2[r]);
        acc2[r] = fmaf(x4.w, w3, acc2[r]);
      }
    }
  }

  {
    const float g2l = ln2g[lane], c2l = ln2b[lane];
#pragma unroll
    for (int r = 0; r < 16; ++r) {
      float s = acc2[r];
      float q = acc2[r] * acc2[r];
#pragma unroll
      for (int off = 32; off; off >>= 1) {
        s += __shfl_xor(s, off, 64);
        q += __shfl_xor(q, off, 64);
      }
      float m = s * (1.0f / 64.0f);
      float var = q * (1.0f / 64.0f) - m * m;
      float inv = rsqrtf(var + 1e-12f);
      float xv = (acc2[r] - m) * inv * g2l + c2l;
      hin[(base + r) * NH + lane] = f2b(fmaxf(xv, 0.0f));
    }
  }
}

// ---------------- K2: bidirectional LSTM via bf16 MFMA -----------------------
// grid (NB/64, 2). Block = 4 waves, 64 batches, one direction.
// Wave w owns hidden units u = w*16 + (lane&15), all 4 gates, weights in VGPRs.
// xA LDS [64 batches][128 (x|h)] bf16, 16B-chunk XOR swizzle to kill bank conflicts.
__global__ __launch_bounds__(256) void k2_lstm(
    const unsigned short* __restrict__ hin,
    const unsigned short* __restrict__ fkT, const float* __restrict__ fwb,
    const unsigned short* __restrict__ bkT, const float* __restrict__ bwb,
    const int* __restrict__ au,
    unsigned short* __restrict__ fwout, unsigned short* __restrict__ bwout) {
  const int tid  = threadIdx.x;
  const int w    = tid >> 6;
  const int lane = tid & 63;
  const int quad = lane >> 4;
  const int l16  = lane & 15;
  const int dir  = blockIdx.y;
  const int batch0 = blockIdx.x * 64;

  __shared__ __align__(16) unsigned short xA[64 * 128];  // 16 KB
  __shared__ int au_s[64];

  const unsigned short* kT   = dir ? bkT : fkT;
  const float*          bias = dir ? bwb : fwb;
  unsigned short*       out  = dir ? bwout : fwout;

  if (tid < 64) au_s[tid] = au[batch0 + tid];
  // zero all of xA (h region must start at 0)
  for (int i = tid; i < 64 * 128 / 2; i += 256) ((unsigned int*)xA)[i] = 0u;

  // B fragments in registers: Bf[gate][kb], n = gate*64 + w*16 + l16
  bf16x8 Bf[4][4];
#pragma unroll
  for (int g = 0; g < 4; ++g) {
    const int n = g * 64 + w * 16 + l16;
#pragma unroll
    for (int kb = 0; kb < 4; ++kb)
      Bf[g][kb] = *(const bf16x8*)&kT[n * 128 + kb * 32 + quad * 8];
  }
  const int u = w * 16 + l16;
  float bg0 = bias[u], bg1 = bias[64 + u], bg2 = bias[128 + u], bg3 = bias[192 + u];

  __syncthreads();

  int aur[16];
#pragma unroll
  for (int mt = 0; mt < 4; ++mt)
#pragma unroll
    for (int r = 0; r < 4; ++r)
      aur[mt * 4 + r] = au_s[mt * 16 + quad * 4 + r];

  float c_s[16], h_s[16];
#pragma unroll
  for (int i = 0; i < 16; ++i) { c_s[i] = 0.0f; h_s[i] = 0.0f; }

  for (int t = 0; t < NT; ++t) {
    // ---- stage x rows: 2 row-chunks per thread ----
#pragma unroll
    for (int rep = 0; rep < 2; ++rep) {
      int r = (tid >> 3) + rep * 32;     // 0..63
      int c8 = tid & 7;                  // 16B chunk within x-part
      int alen = au_s[r];
      int st = (dir == 0) ? t : ((t < alen) ? (alen - 1 - t) : t);
      float4 v = *(const float4*)&hin[((batch0 + r) * NT + st) * NH + c8 * 8];
      *(float4*)&xA[r * 128 + ((c8 ^ (r & 15)) << 3)] = v;
    }
    __syncthreads();

    // ---- gate GEMM: [64,128] x [128, 64-unit 4-gate slice] ----
    f32x4 acc[4][4];
#pragma unroll
    for (int mt = 0; mt < 4; ++mt)
#pragma unroll
      for (int g = 0; g < 4; ++g) acc[mt][g] = 0.0f;

#pragma unroll
    for (int mt = 0; mt < 4; ++mt) {
      const int m = mt * 16 + l16;
      bf16x8 Af[4];
#pragma unroll
      for (int kb = 0; kb < 4; ++kb)
        Af[kb] = *(const bf16x8*)&xA[m * 128 + (((kb * 4 + quad) ^ l16) << 3)];
#pragma unroll
      for (int g = 0; g < 4; ++g)
#pragma unroll
        for (int kb = 0; kb < 4; ++kb)
          acc[mt][g] = __builtin_amdgcn_mfma_f32_16x16x32_bf16(Af[kb], Bf[g][kb],
                                                               acc[mt][g], 0, 0, 0);
    }
    __syncthreads();   // all xA reads done before h-region writes

    // ---- nonlinearity, state update, output + h write ----
#pragma unroll
    for (int mt = 0; mt < 4; ++mt) {
#pragma unroll
      for (int r = 0; r < 4; ++r) {
        const int idx = mt * 4 + r;
        const int bl = mt * 16 + quad * 4 + r;
        const int b = batch0 + bl;
        float gi = acc[mt][0][r] + bg0;
        float gj = acc[mt][1][r] + bg1;
        float gf = acc[mt][2][r] + bg2;
        float go = acc[mt][3][r] + bg3;
        float nc = sigf(gf + 1.0f) * c_s[idx] + sigf(gi) * tanh_fast(gj);
        float nh = sigf(go) * tanh_fast(nc);
        bool valid = t < aur[idx];
        c_s[idx] = valid ? nc : c_s[idx];
        h_s[idx] = valid ? nh : h_s[idx];
        float outv = valid ? nh : 0.0f;
        int pos = (dir == 0) ? t : ((t < aur[idx]) ? (aur[idx] - 1 - t) : t);
        out[(b * NT + pos) * NH + u] = f2b(outv);
        // write carried h into xA for next step (A-layout, swizzled)
        const int e = 64 + u;
        xA[bl * 128 + (((e >> 3) ^ (bl & 15)) << 3) + (e & 7)] = f2b(h_s[idx]);
      }
    }
    __syncthreads();   // h writes complete before next iteration touches xA
  }
}

// ---------------- K3: final LN over (T,2H) + relu + conv dot + masked sum ----
__global__ __launch_bounds__(256) void k3_final(
    const unsigned short* __restrict__ fwout, const unsigned short* __restrict__ bwout,
    const float* __restrict__ ln3g, const float* __restrict__ ln3b,
    const float* __restrict__ conv_w, const float* __restrict__ conv_b,
    const float* __restrict__ mask, float* __restrict__ out) {
  const int wave = threadIdx.x >> 6;
  const int lane = threadIdx.x & 63;
  const int b = blockIdx.x * 4 + wave;

  float f[NT], w[NT];
#pragma unroll
  for (int t = 0; t < NT; ++t) {
    f[t] = b2f(fwout[(b * NT + t) * NH + lane]);
    w[t] = b2f(bwout[(b * NT + t) * NH + lane]);
  }
  float s = 0.0f, q = 0.0f;
#pragma unroll
  for (int t = 0; t < NT; ++t) {
    s += f[t] + w[t];
    q += f[t] * f[t] + w[t] * w[t];
  }
#pragma unroll
  for (int off = 32; off; off >>= 1) {
    s += __shfl_xor(s, off, 64);
    q += __shfl_xor(q, off, 64);
  }
  float m = s * (1.0f / 640.0f);
  float var = q * (1.0f / 640.0f) - m * m;
  float inv = rsqrtf(var + 1e-12f);

  const float gl = ln3g[lane], gh = ln3g[64 + lane];
  const float bl = ln3b[lane], bh = ln3b[64 + lane];
  const float cwl = conv_w[lane], cwh = conv_w[64 + lane];
  const float cb = conv_b[0];

  float Q = 0.0f;
#pragma unroll
  for (int t = 0; t < NT; ++t) {
    float xf = fmaxf((f[t] - m) * inv * gl + bl, 0.0f);
    float xb = fmaxf((w[t] - m) * inv * gh + bh, 0.0f);
    float p = xf * cwl + xb * cwh;
#pragma unroll
    for (int off = 32; off; off >>= 1) p += __shfl_xor(p, off, 64);
    float qv = p + cb;
    Q += qv * mask[b * NT + t];
  }
  if (lane == 0) out[b] = Q;
}

extern "C" void kernel_launch(void* const* d_in, const int* in_sizes, int n_in,
                              void* d_out, int out_size, void* d_ws, size_t ws_size,
                              hipStream_t stream) {
  const float* ud     = (const float*)d_in[0];
  const float* action = (const float*)d_in[1];
  const float* mask   = (const float*)d_in[2];
  const float* ln0g   = (const float*)d_in[3];
  const float* ln0b   = (const float*)d_in[4];
  const float* W1     = (const float*)d_in[5];
  const float* b1     = (const float*)d_in[6];
  const float* ln1g   = (const float*)d_in[7];
  const float* ln1b   = (const float*)d_in[8];
  const float* W2     = (const float*)d_in[9];
  const float* b2     = (const float*)d_in[10];
  const float* ln2g   = (const float*)d_in[11];
  const float* ln2b   = (const float*)d_in[12];
  const float* fwk    = (const float*)d_in[13];
  const float* fwb    = (const float*)d_in[14];
  const float* bwk    = (const float*)d_in[15];
  const float* bwb    = (const float*)d_in[16];
  const float* ln3g   = (const float*)d_in[17];
  const float* ln3b   = (const float*)d_in[18];
  const float* conv_w = (const float*)d_in[19];
  const float* conv_b = (const float*)d_in[20];
  const int*   au     = (const int*)d_in[21];

  const size_t n_hin = (size_t)NB * NT * NH;   // 20,971,520 elements
  unsigned short* hin   = (unsigned short*)d_ws;
  unsigned short* fwout = hin + n_hin;
  unsigned short* bwout = fwout + n_hin;
  unsigned short* fkT   = bwout + n_hin;
  unsigned short* bkT   = fkT + 256 * 128;

  float* outf = (float*)d_out;

  k0_transpose<<<64, 256, 0, stream>>>(fwk, bwk, (unsigned int*)fkT,
                                       (unsigned int*)bkT);
  k1_mlp<<<(NB * NT) / 64, 256, 0, stream>>>(ud, action, ln0g, ln0b, W1, b1,
                                             ln1g, ln1b, W2, b2, ln2g, ln2b, hin);
  k2_lstm<<<dim3(NB / 64, 2), 256, 0, stream>>>(hin, fkT, fwb, bkT, bwb, au,
                                                fwout, bwout);
  k3_final<<<NB / 4, 256, 0, stream>>>(fwout, bwout, ln3g, ln3b, conv_w, conv_b,
                                       mask, outf);
}

// Round 4
// 525.321 us; speedup vs baseline: 2.8494x; 1.3162x over previous
//
#include <hip/hip_runtime.h>
#include <hip/hip_bf16.h>

#define NB    65536
#define NT    5
#define NOBS  128
#define NACT  32
#define NH    64

typedef __attribute__((ext_vector_type(8))) short bf16x8;
typedef __attribute__((ext_vector_type(4))) float f32x4;

__device__ __forceinline__ float sigf(float x) { return 1.0f / (1.0f + __expf(-x)); }
__device__ __forceinline__ float tanh_fast(float x) { return 1.0f - 2.0f / (__expf(2.0f * x) + 1.0f); }

__device__ __forceinline__ unsigned short f2b(float x) {
  __hip_bfloat16 h = __float2bfloat16(x);
  return *(unsigned short*)&h;
}
__device__ __forceinline__ float b2f(unsigned short u) {
  __hip_bfloat16 h = *(__hip_bfloat16*)&u;
  return __bfloat162float(h);
}
__device__ __forceinline__ void split_bf16(float x, unsigned short& h, unsigned short& l) {
  h = f2b(x);
  l = f2b(x - b2f(h));
}

// ---------------- K0: prepare all weight-derived tensors --------------------
// blocks 0..63  : transpose+cast LSTM kernels [128,256] -> [256,128] bf16
//                 (dword-granular ownership: no cross-block sub-dword sharing)
// blocks 64..71 : W1 (g0-folded, hi/lo split) and W2 (hi/lo split) MFMA
//                 B-fragments; u1/vb1 column reductions.
__global__ __launch_bounds__(256) void k0_prep(
    const float* __restrict__ fk, const float* __restrict__ bk,
    const float* __restrict__ W1, const float* __restrict__ W2,
    const float* __restrict__ ln0g, const float* __restrict__ ln0b,
    const float* __restrict__ b1,
    unsigned int* __restrict__ fkT, unsigned int* __restrict__ bkT,
    unsigned short* __restrict__ w1h, unsigned short* __restrict__ w1l,
    unsigned short* __restrict__ w2h, unsigned short* __restrict__ w2l,
    float* __restrict__ u1, float* __restrict__ vb1) {
  const int bx = blockIdx.x;
  if (bx < 64) {
    const int g  = threadIdx.x;          // 0..255 column (gate-unit)
    const int k0 = bx * 2;               // even row
    unsigned int flo = f2b(fk[(k0 + 0) * 256 + g]);
    unsigned int fhi = f2b(fk[(k0 + 1) * 256 + g]);
    unsigned int blo = f2b(bk[(k0 + 0) * 256 + g]);
    unsigned int bhi = f2b(bk[(k0 + 1) * 256 + g]);
    fkT[g * 64 + bx] = flo | (fhi << 16);
    bkT[g * 64 + bx] = blo | (bhi << 16);
    return;
  }
  const int id = (bx - 64) * 256 + threadIdx.x;   // 0..2047
  if (id < 1024) {
    // W1 fragments: frag f = kb*4+nt, lane l; elem j -> k = kb*32+quad*8+j,
    // n = nt*16+l16; value = ln0g[k]*W1[k][n], split hi/lo.
    const int f = id >> 6, l = id & 63;
    const int kb = f >> 2, nt = f & 3;
    const int q = l >> 4, l16 = l & 15;
    const int n = nt * 16 + l16;
    bf16x8 vh, vl;
#pragma unroll
    for (int j = 0; j < 8; ++j) {
      const int k = kb * 32 + q * 8 + j;
      float wg = ln0g[k] * W1[k * 64 + n];
      unsigned short h, lo;
      split_bf16(wg, h, lo);
      vh[j] = (short)h; vl[j] = (short)lo;
    }
    *(bf16x8*)&w1h[(f * 64 + l) * 8] = vh;
    *(bf16x8*)&w1l[(f * 64 + l) * 8] = vl;
  } else if (id < 1792) {
    // W2 fragments: f = kb*4+nt (kb<3)
    const int f = (id - 1024) >> 6, l = id & 63;
    const int kb = f >> 2, nt = f & 3;
    const int q = l >> 4, l16 = l & 15;
    const int n = nt * 16 + l16;
    bf16x8 vh, vl;
#pragma unroll
    for (int j = 0; j < 8; ++j) {
      const int k = kb * 32 + q * 8 + j;   // < 96
      float wv = W2[k * 64 + n];
      unsigned short h, lo;
      split_bf16(wv, h, lo);
      vh[j] = (short)h; vl[j] = (short)lo;
    }
    *(bf16x8*)&w2h[(f * 64 + l) * 8] = vh;
    *(bf16x8*)&w2l[(f * 64 + l) * 8] = vl;
  } else if (id < 1856) {
    const int n = id - 1792;               // 0..63
    float u = 0.0f, vb = 0.0f;
    for (int k = 0; k < 128; ++k) {
      float wv = W1[k * 64 + n];
      u  += ln0g[k] * wv;
      vb += ln0b[k] * wv;
    }
    u1[n]  = u;
    vb1[n] = vb + b1[n];
  }
}

// ---------------- K1: fused MLP via bf16 MFMA (split-precision) -------------
// 4 independent waves/block, 16 rows/wave, zero barriers (wave-private LDS).
// LN0 folded into GEMM1 (Wg trick); row stats via MFMA vs all-ones B-frag.
__global__ __launch_bounds__(256, 2) void k1_mlp(
    const float* __restrict__ ud, const float* __restrict__ action,
    const unsigned short* __restrict__ w1h, const unsigned short* __restrict__ w1l,
    const unsigned short* __restrict__ w2h, const unsigned short* __restrict__ w2l,
    const float* __restrict__ u1, const float* __restrict__ vb1,
    const float* __restrict__ gb2, const float* __restrict__ ln1g,
    const float* __restrict__ ln1b, const float* __restrict__ ln2g,
    const float* __restrict__ ln2b,
    unsigned short* __restrict__ hin) {
  const int wave = threadIdx.x >> 6;
  const int lane = threadIdx.x & 63;
  const int quad = lane >> 4;
  const int l16  = lane & 15;
  const int base = (blockIdx.x * 4 + wave) * 16;

  // [wave][region][16*128]: 0=x_hi 1=x_lo 2=x2_hi 3=x2_lo   (64 KB total)
  __shared__ __align__(16) unsigned short lds[4][4][2048];
  unsigned short* xh  = &lds[wave][0][0];
  unsigned short* xl  = &lds[wave][1][0];
  unsigned short* x2h = &lds[wave][2][0];
  unsigned short* x2l = &lds[wave][3][0];

  // per-lane column parameters (col = nt*16 + l16)
  float u1v[4], vbv[4], g1v[4], c1v[4], b2v[4], g2v[4], c2v[4];
#pragma unroll
  for (int nt = 0; nt < 4; ++nt) {
    const int col = nt * 16 + l16;
    u1v[nt] = u1[col];  vbv[nt] = vb1[col];
    g1v[nt] = ln1g[col]; c1v[nt] = ln1b[col];
    b2v[nt] = gb2[col];
    g2v[nt] = ln2g[col]; c2v[nt] = ln2b[col];
  }

  // ---- stage action -> x2 region chunks 8..11 (split hi/lo) ----
  {
    const int arow = lane >> 2, ag = lane & 3;
    const float* ap = &action[(size_t)(base + arow) * NACT + ag * 8];
    float4 a0 = *(const float4*)ap;
    float4 a1 = *(const float4*)(ap + 4);
    float av[8] = {a0.x, a0.y, a0.z, a0.w, a1.x, a1.y, a1.z, a1.w};
    bf16x8 vh, vl;
#pragma unroll
    for (int j = 0; j < 8; ++j) {
      unsigned short h, lo;
      split_bf16(av[j], h, lo);
      vh[j] = (short)h; vl[j] = (short)lo;
    }
    const int idx = arow * 128 + (((8 + ag) ^ (arow & 15)) << 3);
    *(bf16x8*)&x2h[idx] = vh;
    *(bf16x8*)&x2l[idx] = vl;
  }

  // ---- stage raw x (split hi/lo, swizzled chunks) ----
#pragma unroll
  for (int r = 0; r < 16; ++r) {
    float2 xx = *(const float2*)&ud[(size_t)(base + r) * NOBS + 2 * lane];
    unsigned short h0, l0, h1, l1;
    split_bf16(xx.x, h0, l0);
    split_bf16(xx.y, h1, l1);
    const int di = r * 64 + (((lane >> 2) ^ (r & 15)) << 2) + (lane & 3);
    ((unsigned int*)xh)[di] = (unsigned int)h0 | ((unsigned int)h1 << 16);
    ((unsigned int*)xl)[di] = (unsigned int)l0 | ((unsigned int)l1 << 16);
  }

  // ---- W1 fragments (hi+lo held in regs) ----
  bf16x8 W1hf[16], W1lf[16];
#pragma unroll
  for (int f = 0; f < 16; ++f) {
    W1hf[f] = *(const bf16x8*)&w1h[(f * 64 + lane) * 8];
    W1lf[f] = *(const bf16x8*)&w1l[(f * 64 + lane) * 8];
  }

  bf16x8 ones;
#pragma unroll
  for (int j = 0; j < 8; ++j) ones[j] = (short)0x3F80;   // bf16 1.0

  // ---- GEMM1 + row stats ----
  f32x4 acc[4], s_acc, q_acc;
#pragma unroll
  for (int nt = 0; nt < 4; ++nt) acc[nt] = 0.0f;
  s_acc = 0.0f; q_acc = 0.0f;

#pragma unroll
  for (int kb = 0; kb < 4; ++kb) {
    const int ai = l16 * 128 + (((kb * 4 + quad) ^ l16) << 3);
    bf16x8 Ah = *(const bf16x8*)&xh[ai];
    bf16x8 Al = *(const bf16x8*)&xl[ai];
    bf16x8 Asq;
#pragma unroll
    for (int j = 0; j < 8; ++j) {
      unsigned int uu = ((unsigned int)(unsigned short)Ah[j]) << 16;
      float v = __uint_as_float(uu);
      v *= v;
      Asq[j] = (short)(unsigned short)(__float_as_uint(v) >> 16);
    }
    s_acc = __builtin_amdgcn_mfma_f32_16x16x32_bf16(Ah, ones, s_acc, 0, 0, 0);
    s_acc = __builtin_amdgcn_mfma_f32_16x16x32_bf16(Al, ones, s_acc, 0, 0, 0);
    q_acc = __builtin_amdgcn_mfma_f32_16x16x32_bf16(Asq, ones, q_acc, 0, 0, 0);
#pragma unroll
    for (int nt = 0; nt < 4; ++nt) {
      const int f = kb * 4 + nt;
      acc[nt] = __builtin_amdgcn_mfma_f32_16x16x32_bf16(Ah, W1hf[f], acc[nt], 0, 0, 0);
      acc[nt] = __builtin_amdgcn_mfma_f32_16x16x32_bf16(Ah, W1lf[f], acc[nt], 0, 0, 0);
      acc[nt] = __builtin_amdgcn_mfma_f32_16x16x32_bf16(Al, W1hf[f], acc[nt], 0, 0, 0);
    }
  }

  // ---- LN0 fixup (per-row affine) + LN1 + relu ----
  float inv0[4], ivm[4];
#pragma unroll
  for (int r = 0; r < 4; ++r) {
    float m   = s_acc[r] * (1.0f / 128.0f);
    float var = q_acc[r] * (1.0f / 128.0f) - m * m;
    float inv = rsqrtf(var + 1e-12f);
    inv0[r] = inv;
    ivm[r]  = inv * m;
  }
  float y[4][4];   // [nt][r]
#pragma unroll
  for (int nt = 0; nt < 4; ++nt)
#pragma unroll
    for (int r = 0; r < 4; ++r)
      y[nt][r] = fmaf(inv0[r], acc[nt][r], fmaf(-ivm[r], u1v[nt], vbv[nt]));

  float m1[4], i1[4];
#pragma unroll
  for (int r = 0; r < 4; ++r) {
    float s1 = y[0][r] + y[1][r] + y[2][r] + y[3][r];
    float q1 = y[0][r] * y[0][r] + y[1][r] * y[1][r] +
               y[2][r] * y[2][r] + y[3][r] * y[3][r];
#pragma unroll
    for (int off = 1; off <= 8; off <<= 1) {
      s1 += __shfl_xor(s1, off, 64);
      q1 += __shfl_xor(q1, off, 64);
    }
    float mm = s1 * (1.0f / 64.0f);
    m1[r] = mm;
    i1[r] = rsqrtf(q1 * (1.0f / 64.0f) - mm * mm + 1e-12f);
  }

#pragma unroll
  for (int nt = 0; nt < 4; ++nt)
#pragma unroll
    for (int r = 0; r < 4; ++r) {
      float x1 = fmaxf(0.0f, fmaf((y[nt][r] - m1[r]) * i1[r], g1v[nt], c1v[nt]));
      unsigned short h, lo;
      split_bf16(x1, h, lo);
      const int row = quad * 4 + r;
      const int idx = row * 128 + (((nt * 2 + (l16 >> 3)) ^ (row & 15)) << 3) + (l16 & 7);
      x2h[idx] = h;
      x2l[idx] = lo;
    }

  // ---- GEMM2 (K=96, W2 frags streamed per ktile) ----
  f32x4 acc2[4];
#pragma unroll
  for (int nt = 0; nt < 4; ++nt) acc2[nt] = 0.0f;

#pragma unroll
  for (int kb = 0; kb < 3; ++kb) {
    bf16x8 w2hf[4], w2lf[4];
#pragma unroll
    for (int nt = 0; nt < 4; ++nt) {
      const int f = kb * 4 + nt;
      w2hf[nt] = *(const bf16x8*)&w2h[(f * 64 + lane) * 8];
      w2lf[nt] = *(const bf16x8*)&w2l[(f * 64 + lane) * 8];
    }
    const int ai = l16 * 128 + (((kb * 4 + quad) ^ l16) << 3);
    bf16x8 Ah = *(const bf16x8*)&x2h[ai];
    bf16x8 Al = *(const bf16x8*)&x2l[ai];
#pragma unroll
    for (int nt = 0; nt < 4; ++nt) {
      acc2[nt] = __builtin_amdgcn_mfma_f32_16x16x32_bf16(Ah, w2hf[nt], acc2[nt], 0, 0, 0);
      acc2[nt] = __builtin_amdgcn_mfma_f32_16x16x32_bf16(Ah, w2lf[nt], acc2[nt], 0, 0, 0);
      acc2[nt] = __builtin_amdgcn_mfma_f32_16x16x32_bf16(Al, w2hf[nt], acc2[nt], 0, 0, 0);
    }
  }

  // ---- + b2, LN2, relu, store ----
  float y2[4][4];
#pragma unroll
  for (int nt = 0; nt < 4; ++nt)
#pragma unroll
    for (int r = 0; r < 4; ++r)
      y2[nt][r] = acc2[nt][r] + b2v[nt];

  float m2[4], i2[4];
#pragma unroll
  for (int r = 0; r < 4; ++r) {
    float s2 = y2[0][r] + y2[1][r] + y2[2][r] + y2[3][r];
    float q2 = y2[0][r] * y2[0][r] + y2[1][r] * y2[1][r] +
               y2[2][r] * y2[2][r] + y2[3][r] * y2[3][r];
#pragma unroll
    for (int off = 1; off <= 8; off <<= 1) {
      s2 += __shfl_xor(s2, off, 64);
      q2 += __shfl_xor(q2, off, 64);
    }
    float mm = s2 * (1.0f / 64.0f);
    m2[r] = mm;
    i2[r] = rsqrtf(q2 * (1.0f / 64.0f) - mm * mm + 1e-12f);
  }

#pragma unroll
  for (int nt = 0; nt < 4; ++nt)
#pragma unroll
    for (int r = 0; r < 4; ++r) {
      float o = fmaxf(0.0f, fmaf((y2[nt][r] - m2[r]) * i2[r], g2v[nt], c2v[nt]));
      const int row = quad * 4 + r;
      hin[(size_t)(base + row) * NH + nt * 16 + l16] = f2b(o);
    }
}

// ---------------- K2: bidirectional LSTM via bf16 MFMA (unchanged) ----------
__global__ __launch_bounds__(256) void k2_lstm(
    const unsigned short* __restrict__ hin,
    const unsigned short* __restrict__ fkT, const float* __restrict__ fwb,
    const unsigned short* __restrict__ bkT, const float* __restrict__ bwb,
    const int* __restrict__ au,
    unsigned short* __restrict__ fwout, unsigned short* __restrict__ bwout) {
  const int tid  = threadIdx.x;
  const int w    = tid >> 6;
  const int lane = tid & 63;
  const int quad = lane >> 4;
  const int l16  = lane & 15;
  const int dir  = blockIdx.y;
  const int batch0 = blockIdx.x * 64;

  __shared__ __align__(16) unsigned short xA[64 * 128];  // 16 KB
  __shared__ int au_s[64];

  const unsigned short* kT   = dir ? bkT : fkT;
  const float*          bias = dir ? bwb : fwb;
  unsigned short*       out  = dir ? bwout : fwout;

  if (tid < 64) au_s[tid] = au[batch0 + tid];
  for (int i = tid; i < 64 * 128 / 2; i += 256) ((unsigned int*)xA)[i] = 0u;

  bf16x8 Bf[4][4];
#pragma unroll
  for (int g = 0; g < 4; ++g) {
    const int n = g * 64 + w * 16 + l16;
#pragma unroll
    for (int kb = 0; kb < 4; ++kb)
      Bf[g][kb] = *(const bf16x8*)&kT[n * 128 + kb * 32 + quad * 8];
  }
  const int u = w * 16 + l16;
  float bg0 = bias[u], bg1 = bias[64 + u], bg2 = bias[128 + u], bg3 = bias[192 + u];

  __syncthreads();

  int aur[16];
#pragma unroll
  for (int mt = 0; mt < 4; ++mt)
#pragma unroll
    for (int r = 0; r < 4; ++r)
      aur[mt * 4 + r] = au_s[mt * 16 + quad * 4 + r];

  float c_s[16], h_s[16];
#pragma unroll
  for (int i = 0; i < 16; ++i) { c_s[i] = 0.0f; h_s[i] = 0.0f; }

  for (int t = 0; t < NT; ++t) {
#pragma unroll
    for (int rep = 0; rep < 2; ++rep) {
      int r = (tid >> 3) + rep * 32;
      int c8 = tid & 7;
      int alen = au_s[r];
      int st = (dir == 0) ? t : ((t < alen) ? (alen - 1 - t) : t);
      float4 v = *(const float4*)&hin[((batch0 + r) * NT + st) * NH + c8 * 8];
      *(float4*)&xA[r * 128 + ((c8 ^ (r & 15)) << 3)] = v;
    }
    __syncthreads();

    f32x4 acc[4][4];
#pragma unroll
    for (int mt = 0; mt < 4; ++mt)
#pragma unroll
      for (int g = 0; g < 4; ++g) acc[mt][g] = 0.0f;

#pragma unroll
    for (int mt = 0; mt < 4; ++mt) {
      const int m = mt * 16 + l16;
      bf16x8 Af[4];
#pragma unroll
      for (int kb = 0; kb < 4; ++kb)
        Af[kb] = *(const bf16x8*)&xA[m * 128 + (((kb * 4 + quad) ^ l16) << 3)];
#pragma unroll
      for (int g = 0; g < 4; ++g)
#pragma unroll
        for (int kb = 0; kb < 4; ++kb)
          acc[mt][g] = __builtin_amdgcn_mfma_f32_16x16x32_bf16(Af[kb], Bf[g][kb],
                                                               acc[mt][g], 0, 0, 0);
    }
    __syncthreads();

#pragma unroll
    for (int mt = 0; mt < 4; ++mt) {
#pragma unroll
      for (int r = 0; r < 4; ++r) {
        const int idx = mt * 4 + r;
        const int bl = mt * 16 + quad * 4 + r;
        const int b = batch0 + bl;
        float gi = acc[mt][0][r] + bg0;
        float gj = acc[mt][1][r] + bg1;
        float gf = acc[mt][2][r] + bg2;
        float go = acc[mt][3][r] + bg3;
        float nc = sigf(gf + 1.0f) * c_s[idx] + sigf(gi) * tanh_fast(gj);
        float nh = sigf(go) * tanh_fast(nc);
        bool valid = t < aur[idx];
        c_s[idx] = valid ? nc : c_s[idx];
        h_s[idx] = valid ? nh : h_s[idx];
        float outv = valid ? nh : 0.0f;
        int pos = (dir == 0) ? t : ((t < aur[idx]) ? (aur[idx] - 1 - t) : t);
        out[(b * NT + pos) * NH + u] = f2b(outv);
        const int e = 64 + u;
        xA[bl * 128 + (((e >> 3) ^ (bl & 15)) << 3) + (e & 7)] = f2b(h_s[idx]);
      }
    }
    __syncthreads();
  }
}

// ---------------- K3: final LN over (T,2H) + relu + conv dot + masked sum ----
__global__ __launch_bounds__(256) void k3_final(
    const unsigned short* __restrict__ fwout, const unsigned short* __restrict__ bwout,
    const float* __restrict__ ln3g, const float* __restrict__ ln3b,
    const float* __restrict__ conv_w, const float* __restrict__ conv_b,
    const float* __restrict__ mask, float* __restrict__ out) {
  const int wave = threadIdx.x >> 6;
  const int lane = threadIdx.x & 63;
  const int b = blockIdx.x * 4 + wave;

  float f[NT], w[NT];
#pragma unroll
  for (int t = 0; t < NT; ++t) {
    f[t] = b2f(fwout[(b * NT + t) * NH + lane]);
    w[t] = b2f(bwout[(b * NT + t) * NH + lane]);
  }
  float s = 0.0f, q = 0.0f;
#pragma unroll
  for (int t = 0; t < NT; ++t) {
    s += f[t] + w[t];
    q += f[t] * f[t] + w[t] * w[t];
  }
#pragma unroll
  for (int off = 32; off; off >>= 1) {
    s += __shfl_xor(s, off, 64);
    q += __shfl_xor(q, off, 64);
  }
  float m = s * (1.0f / 640.0f);
  float var = q * (1.0f / 640.0f) - m * m;
  float inv = rsqrtf(var + 1e-12f);

  const float gl = ln3g[lane], gh = ln3g[64 + lane];
  const float bl = ln3b[lane], bh = ln3b[64 + lane];
  const float cwl = conv_w[lane], cwh = conv_w[64 + lane];
  const float cb = conv_b[0];

  float Q = 0.0f;
#pragma unroll
  for (int t = 0; t < NT; ++t) {
    float xf = fmaxf((f[t] - m) * inv * gl + bl, 0.0f);
    float xb = fmaxf((w[t] - m) * inv * gh + bh, 0.0f);
    float p = xf * cwl + xb * cwh;
#pragma unroll
    for (int off = 32; off; off >>= 1) p += __shfl_xor(p, off, 64);
    float qv = p + cb;
    Q += qv * mask[b * NT + t];
  }
  if (lane == 0) out[b] = Q;
}

extern "C" void kernel_launch(void* const* d_in, const int* in_sizes, int n_in,
                              void* d_out, int out_size, void* d_ws, size_t ws_size,
                              hipStream_t stream) {
  const float* ud     = (const float*)d_in[0];
  const float* action = (const float*)d_in[1];
  const float* mask   = (const float*)d_in[2];
  const float* ln0g   = (const float*)d_in[3];
  const float* ln0b   = (const float*)d_in[4];
  const float* W1     = (const float*)d_in[5];
  const float* b1     = (const float*)d_in[6];
  const float* ln1g   = (const float*)d_in[7];
  const float* ln1b   = (const float*)d_in[8];
  const float* W2     = (const float*)d_in[9];
  const float* b2     = (const float*)d_in[10];
  const float* ln2g   = (const float*)d_in[11];
  const float* ln2b   = (const float*)d_in[12];
  const float* fwk    = (const float*)d_in[13];
  const float* fwb    = (const float*)d_in[14];
  const float* bwk    = (const float*)d_in[15];
  const float* bwb    = (const float*)d_in[16];
  const float* ln3g   = (const float*)d_in[17];
  const float* ln3b   = (const float*)d_in[18];
  const float* conv_w = (const float*)d_in[19];
  const float* conv_b = (const float*)d_in[20];
  const int*   au     = (const int*)d_in[21];

  const size_t n_hin = (size_t)NB * NT * NH;   // 20,971,520 elements
  unsigned short* wsu   = (unsigned short*)d_ws;
  unsigned short* hin   = wsu;
  unsigned short* fwout = hin + n_hin;
  unsigned short* bwout = fwout + n_hin;
  unsigned short* fkT   = bwout + n_hin;          // 32768
  unsigned short* bkT   = fkT + 32768;            // 32768
  unsigned short* w1h   = bkT + 32768;            // 8192
  unsigned short* w1l   = w1h + 8192;             // 8192
  unsigned short* w2h   = w1l + 8192;             // 6144
  unsigned short* w2l   = w2h + 6144;             // 6144
  float*          u1    = (float*)(w2l + 6144);   // 64
  float*          vb1   = u1 + 64;                // 64

  float* outf = (float*)d_out;

  k0_prep<<<72, 256, 0, stream>>>(fwk, bwk, W1, W2, ln0g, ln0b, b1,
                                  (unsigned int*)fkT, (unsigned int*)bkT,
                                  w1h, w1l, w2h, w2l, u1, vb1);
  k1_mlp<<<(NB * NT) / 64, 256, 0, stream>>>(ud, action, w1h, w1l, w2h, w2l,
                                             u1, vb1, b2, ln1g, ln1b, ln2g, ln2b,
                                             hin);
  k2_lstm<<<dim3(NB / 64, 2), 256, 0, stream>>>(hin, fkT, fwb, bkT, bwb, au,
                                                fwout, bwout);
  k3_final<<<NB / 4, 256, 0, stream>>>(fwout, bwout, ln3g, ln3b, conv_w, conv_b,
                                       mask, outf);
}

// Round 5
// 520.407 us; speedup vs baseline: 2.8763x; 1.0094x over previous
//
#include <hip/hip_runtime.h>
#include <hip/hip_bf16.h>

#define NB    65536
#define NT    5
#define NOBS  128
#define NACT  32
#define NH    64

typedef __attribute__((ext_vector_type(8))) short bf16x8;
typedef __attribute__((ext_vector_type(4))) float f32x4;

__device__ __forceinline__ float sigf(float x) { return 1.0f / (1.0f + __expf(-x)); }
__device__ __forceinline__ float tanh_fast(float x) { return 1.0f - 2.0f / (__expf(2.0f * x) + 1.0f); }

__device__ __forceinline__ unsigned short f2b(float x) {
  __hip_bfloat16 h = __float2bfloat16(x);
  return *(unsigned short*)&h;
}
__device__ __forceinline__ float b2f(unsigned short u) {
  __hip_bfloat16 h = *(__hip_bfloat16*)&u;
  return __bfloat162float(h);
}
__device__ __forceinline__ void split_bf16(float x, unsigned short& h, unsigned short& l) {
  h = f2b(x);
  l = f2b(x - b2f(h));
}

// ---------------- K0: prepare all weight-derived tensors --------------------
__global__ __launch_bounds__(256) void k0_prep(
    const float* __restrict__ fk, const float* __restrict__ bk,
    const float* __restrict__ W1, const float* __restrict__ W2,
    const float* __restrict__ ln0g, const float* __restrict__ ln0b,
    const float* __restrict__ b1,
    unsigned int* __restrict__ fkT, unsigned int* __restrict__ bkT,
    unsigned short* __restrict__ w1h, unsigned short* __restrict__ w1l,
    unsigned short* __restrict__ w2h, unsigned short* __restrict__ w2l,
    float* __restrict__ u1, float* __restrict__ vb1) {
  const int bx = blockIdx.x;
  if (bx < 64) {
    const int g  = threadIdx.x;          // 0..255 column (gate-unit)
    const int k0 = bx * 2;               // even row
    unsigned int flo = f2b(fk[(k0 + 0) * 256 + g]);
    unsigned int fhi = f2b(fk[(k0 + 1) * 256 + g]);
    unsigned int blo = f2b(bk[(k0 + 0) * 256 + g]);
    unsigned int bhi = f2b(bk[(k0 + 1) * 256 + g]);
    fkT[g * 64 + bx] = flo | (fhi << 16);
    bkT[g * 64 + bx] = blo | (bhi << 16);
    return;
  }
  const int id = (bx - 64) * 256 + threadIdx.x;   // 0..2047
  if (id < 1024) {
    const int f = id >> 6, l = id & 63;
    const int kb = f >> 2, nt = f & 3;
    const int q = l >> 4, l16 = l & 15;
    const int n = nt * 16 + l16;
    bf16x8 vh, vl;
#pragma unroll
    for (int j = 0; j < 8; ++j) {
      const int k = kb * 32 + q * 8 + j;
      float wg = ln0g[k] * W1[k * 64 + n];
      unsigned short h, lo;
      split_bf16(wg, h, lo);
      vh[j] = (short)h; vl[j] = (short)lo;
    }
    *(bf16x8*)&w1h[(f * 64 + l) * 8] = vh;
    *(bf16x8*)&w1l[(f * 64 + l) * 8] = vl;
  } else if (id < 1792) {
    const int f = (id - 1024) >> 6, l = id & 63;
    const int kb = f >> 2, nt = f & 3;
    const int q = l >> 4, l16 = l & 15;
    const int n = nt * 16 + l16;
    bf16x8 vh, vl;
#pragma unroll
    for (int j = 0; j < 8; ++j) {
      const int k = kb * 32 + q * 8 + j;   // < 96
      float wv = W2[k * 64 + n];
      unsigned short h, lo;
      split_bf16(wv, h, lo);
      vh[j] = (short)h; vl[j] = (short)lo;
    }
    *(bf16x8*)&w2h[(f * 64 + l) * 8] = vh;
    *(bf16x8*)&w2l[(f * 64 + l) * 8] = vl;
  } else if (id < 1856) {
    const int n = id - 1792;               // 0..63
    float u = 0.0f, vb = 0.0f;
    for (int k = 0; k < 128; ++k) {
      float wv = W1[k * 64 + n];
      u  += ln0g[k] * wv;
      vb += ln0b[k] * wv;
    }
    u1[n]  = u;
    vb1[n] = vb + b1[n];
  }
}

// ---------------- K1: fused MLP via bf16 MFMA (split-precision) -------------
__global__ __launch_bounds__(256, 2) void k1_mlp(
    const float* __restrict__ ud, const float* __restrict__ action,
    const unsigned short* __restrict__ w1h, const unsigned short* __restrict__ w1l,
    const unsigned short* __restrict__ w2h, const unsigned short* __restrict__ w2l,
    const float* __restrict__ u1, const float* __restrict__ vb1,
    const float* __restrict__ gb2, const float* __restrict__ ln1g,
    const float* __restrict__ ln1b, const float* __restrict__ ln2g,
    const float* __restrict__ ln2b,
    unsigned short* __restrict__ hin) {
  const int wave = threadIdx.x >> 6;
  const int lane = threadIdx.x & 63;
  const int quad = lane >> 4;
  const int l16  = lane & 15;
  const int base = (blockIdx.x * 4 + wave) * 16;

  __shared__ __align__(16) unsigned short lds[4][4][2048];
  unsigned short* xh  = &lds[wave][0][0];
  unsigned short* xl  = &lds[wave][1][0];
  unsigned short* x2h = &lds[wave][2][0];
  unsigned short* x2l = &lds[wave][3][0];

  float u1v[4], vbv[4], g1v[4], c1v[4], b2v[4], g2v[4], c2v[4];
#pragma unroll
  for (int nt = 0; nt < 4; ++nt) {
    const int col = nt * 16 + l16;
    u1v[nt] = u1[col];  vbv[nt] = vb1[col];
    g1v[nt] = ln1g[col]; c1v[nt] = ln1b[col];
    b2v[nt] = gb2[col];
    g2v[nt] = ln2g[col]; c2v[nt] = ln2b[col];
  }

  {
    const int arow = lane >> 2, ag = lane & 3;
    const float* ap = &action[(size_t)(base + arow) * NACT + ag * 8];
    float4 a0 = *(const float4*)ap;
    float4 a1 = *(const float4*)(ap + 4);
    float av[8] = {a0.x, a0.y, a0.z, a0.w, a1.x, a1.y, a1.z, a1.w};
    bf16x8 vh, vl;
#pragma unroll
    for (int j = 0; j < 8; ++j) {
      unsigned short h, lo;
      split_bf16(av[j], h, lo);
      vh[j] = (short)h; vl[j] = (short)lo;
    }
    const int idx = arow * 128 + (((8 + ag) ^ (arow & 15)) << 3);
    *(bf16x8*)&x2h[idx] = vh;
    *(bf16x8*)&x2l[idx] = vl;
  }

#pragma unroll
  for (int r = 0; r < 16; ++r) {
    float2 xx = *(const float2*)&ud[(size_t)(base + r) * NOBS + 2 * lane];
    unsigned short h0, l0, h1, l1;
    split_bf16(xx.x, h0, l0);
    split_bf16(xx.y, h1, l1);
    const int di = r * 64 + (((lane >> 2) ^ (r & 15)) << 2) + (lane & 3);
    ((unsigned int*)xh)[di] = (unsigned int)h0 | ((unsigned int)h1 << 16);
    ((unsigned int*)xl)[di] = (unsigned int)l0 | ((unsigned int)l1 << 16);
  }

  bf16x8 W1hf[16], W1lf[16];
#pragma unroll
  for (int f = 0; f < 16; ++f) {
    W1hf[f] = *(const bf16x8*)&w1h[(f * 64 + lane) * 8];
    W1lf[f] = *(const bf16x8*)&w1l[(f * 64 + lane) * 8];
  }

  bf16x8 ones;
#pragma unroll
  for (int j = 0; j < 8; ++j) ones[j] = (short)0x3F80;

  f32x4 acc[4], s_acc, q_acc;
#pragma unroll
  for (int nt = 0; nt < 4; ++nt) acc[nt] = 0.0f;
  s_acc = 0.0f; q_acc = 0.0f;

#pragma unroll
  for (int kb = 0; kb < 4; ++kb) {
    const int ai = l16 * 128 + (((kb * 4 + quad) ^ l16) << 3);
    bf16x8 Ah = *(const bf16x8*)&xh[ai];
    bf16x8 Al = *(const bf16x8*)&xl[ai];
    bf16x8 Asq;
#pragma unroll
    for (int j = 0; j < 8; ++j) {
      unsigned int uu = ((unsigned int)(unsigned short)Ah[j]) << 16;
      float v = __uint_as_float(uu);
      v *= v;
      Asq[j] = (short)(unsigned short)(__float_as_uint(v) >> 16);
    }
    s_acc = __builtin_amdgcn_mfma_f32_16x16x32_bf16(Ah, ones, s_acc, 0, 0, 0);
    s_acc = __builtin_amdgcn_mfma_f32_16x16x32_bf16(Al, ones, s_acc, 0, 0, 0);
    q_acc = __builtin_amdgcn_mfma_f32_16x16x32_bf16(Asq, ones, q_acc, 0, 0, 0);
#pragma unroll
    for (int nt = 0; nt < 4; ++nt) {
      const int f = kb * 4 + nt;
      acc[nt] = __builtin_amdgcn_mfma_f32_16x16x32_bf16(Ah, W1hf[f], acc[nt], 0, 0, 0);
      acc[nt] = __builtin_amdgcn_mfma_f32_16x16x32_bf16(Ah, W1lf[f], acc[nt], 0, 0, 0);
      acc[nt] = __builtin_amdgcn_mfma_f32_16x16x32_bf16(Al, W1hf[f], acc[nt], 0, 0, 0);
    }
  }

  float inv0[4], ivm[4];
#pragma unroll
  for (int r = 0; r < 4; ++r) {
    float m   = s_acc[r] * (1.0f / 128.0f);
    float var = q_acc[r] * (1.0f / 128.0f) - m * m;
    float inv = rsqrtf(var + 1e-12f);
    inv0[r] = inv;
    ivm[r]  = inv * m;
  }
  float y[4][4];
#pragma unroll
  for (int nt = 0; nt < 4; ++nt)
#pragma unroll
    for (int r = 0; r < 4; ++r)
      y[nt][r] = fmaf(inv0[r], acc[nt][r], fmaf(-ivm[r], u1v[nt], vbv[nt]));

  float m1[4], i1[4];
#pragma unroll
  for (int r = 0; r < 4; ++r) {
    float s1 = y[0][r] + y[1][r] + y[2][r] + y[3][r];
    float q1 = y[0][r] * y[0][r] + y[1][r] * y[1][r] +
               y[2][r] * y[2][r] + y[3][r] * y[3][r];
#pragma unroll
    for (int off = 1; off <= 8; off <<= 1) {
      s1 += __shfl_xor(s1, off, 64);
      q1 += __shfl_xor(q1, off, 64);
    }
    float mm = s1 * (1.0f / 64.0f);
    m1[r] = mm;
    i1[r] = rsqrtf(q1 * (1.0f / 64.0f) - mm * mm + 1e-12f);
  }

#pragma unroll
  for (int nt = 0; nt < 4; ++nt)
#pragma unroll
    for (int r = 0; r < 4; ++r) {
      float x1 = fmaxf(0.0f, fmaf((y[nt][r] - m1[r]) * i1[r], g1v[nt], c1v[nt]));
      unsigned short h, lo;
      split_bf16(x1, h, lo);
      const int row = quad * 4 + r;
      const int idx = row * 128 + (((nt * 2 + (l16 >> 3)) ^ (row & 15)) << 3) + (l16 & 7);
      x2h[idx] = h;
      x2l[idx] = lo;
    }

  f32x4 acc2[4];
#pragma unroll
  for (int nt = 0; nt < 4; ++nt) acc2[nt] = 0.0f;

#pragma unroll
  for (int kb = 0; kb < 3; ++kb) {
    bf16x8 w2hf[4], w2lf[4];
#pragma unroll
    for (int nt = 0; nt < 4; ++nt) {
      const int f = kb * 4 + nt;
      w2hf[nt] = *(const bf16x8*)&w2h[(f * 64 + lane) * 8];
      w2lf[nt] = *(const bf16x8*)&w2l[(f * 64 + lane) * 8];
    }
    const int ai = l16 * 128 + (((kb * 4 + quad) ^ l16) << 3);
    bf16x8 Ah = *(const bf16x8*)&x2h[ai];
    bf16x8 Al = *(const bf16x8*)&x2l[ai];
#pragma unroll
    for (int nt = 0; nt < 4; ++nt) {
      acc2[nt] = __builtin_amdgcn_mfma_f32_16x16x32_bf16(Ah, w2hf[nt], acc2[nt], 0, 0, 0);
      acc2[nt] = __builtin_amdgcn_mfma_f32_16x16x32_bf16(Ah, w2lf[nt], acc2[nt], 0, 0, 0);
      acc2[nt] = __builtin_amdgcn_mfma_f32_16x16x32_bf16(Al, w2hf[nt], acc2[nt], 0, 0, 0);
    }
  }

  float y2[4][4];
#pragma unroll
  for (int nt = 0; nt < 4; ++nt)
#pragma unroll
    for (int r = 0; r < 4; ++r)
      y2[nt][r] = acc2[nt][r] + b2v[nt];

  float m2[4], i2[4];
#pragma unroll
  for (int r = 0; r < 4; ++r) {
    float s2 = y2[0][r] + y2[1][r] + y2[2][r] + y2[3][r];
    float q2 = y2[0][r] * y2[0][r] + y2[1][r] * y2[1][r] +
               y2[2][r] * y2[2][r] + y2[3][r] * y2[3][r];
#pragma unroll
    for (int off = 1; off <= 8; off <<= 1) {
      s2 += __shfl_xor(s2, off, 64);
      q2 += __shfl_xor(q2, off, 64);
    }
    float mm = s2 * (1.0f / 64.0f);
    m2[r] = mm;
    i2[r] = rsqrtf(q2 * (1.0f / 64.0f) - mm * mm + 1e-12f);
  }

#pragma unroll
  for (int nt = 0; nt < 4; ++nt)
#pragma unroll
    for (int r = 0; r < 4; ++r) {
      float o = fmaxf(0.0f, fmaf((y2[nt][r] - m2[r]) * i2[r], g2v[nt], c2v[nt]));
      const int row = quad * 4 + r;
      hin[(size_t)(base + row) * NH + nt * 16 + l16] = f2b(o);
    }
}

// ---------------- K23: fused bidirectional LSTM + LN3/conv/mask -------------
// grid NB/32. Block = 4 waves, 32 batches, BOTH directions.
// fw/bw outputs stay in LDS obuf (bf16); final reduction done in-block.
// x A-fragments load directly from global (prefetched 1 step ahead);
// h carried via 4 KB swizzled LDS.
__global__ __launch_bounds__(256, 2) void k23_lstm_final(
    const unsigned short* __restrict__ hin,
    const unsigned short* __restrict__ fkT, const float* __restrict__ fwb,
    const unsigned short* __restrict__ bkT, const float* __restrict__ bwb,
    const int* __restrict__ au,
    const float* __restrict__ ln3g, const float* __restrict__ ln3b,
    const float* __restrict__ conv_w, const float* __restrict__ conv_b,
    const float* __restrict__ mask, float* __restrict__ out) {
  const int tid  = threadIdx.x;
  const int w    = tid >> 6;
  const int lane = tid & 63;
  const int quad = lane >> 4;
  const int l16  = lane & 15;
  const int batch0 = blockIdx.x * 32;

  __shared__ __align__(16) unsigned short obuf[10 * 32 * 64];  // 40 KB
  __shared__ __align__(16) unsigned short hA[32 * 64];         //  4 KB

  const int u = w * 16 + l16;

  // per-lane sequence lengths
  const int aum0 = au[batch0 + l16];
  const int aum1 = au[batch0 + 16 + l16];
  int aur[8];
#pragma unroll
  for (int mt = 0; mt < 2; ++mt)
#pragma unroll
    for (int r = 0; r < 4; ++r)
      aur[mt * 4 + r] = au[batch0 + mt * 16 + quad * 4 + r];

  for (int dir = 0; dir < 2; ++dir) {
    const unsigned short* kT   = dir ? bkT : fkT;
    const float*          bias = dir ? bwb : fwb;

    bf16x8 Bf[4][4];
#pragma unroll
    for (int g = 0; g < 4; ++g) {
      const int n = g * 64 + u;
#pragma unroll
      for (int kb = 0; kb < 4; ++kb)
        Bf[g][kb] = *(const bf16x8*)&kT[n * 128 + kb * 32 + quad * 8];
    }
    const float bg0 = bias[u], bg1 = bias[64 + u];
    const float bg2 = bias[128 + u], bg3 = bias[192 + u];

    __syncthreads();                       // prior dir's hA writes done
    *(float4*)&hA[tid * 8] = make_float4(0.f, 0.f, 0.f, 0.f);
    float c_s[8], h_s[8];
#pragma unroll
    for (int i = 0; i < 8; ++i) { c_s[i] = 0.0f; h_s[i] = 0.0f; }
    __syncthreads();                       // hA zero visible

    // prefetch x fragments for t=0 (au >= 1 so t=0 always valid)
    bf16x8 Ax0[2], Ax1[2];
#pragma unroll
    for (int mt = 0; mt < 2; ++mt) {
      const int m = mt * 16 + l16;
      const int a = mt ? aum1 : aum0;
      const int st = dir ? (a - 1) : 0;
      const size_t rb = ((size_t)(batch0 + m) * NT + st) * NH;
      Ax0[mt] = *(const bf16x8*)&hin[rb + quad * 8];
      Ax1[mt] = *(const bf16x8*)&hin[rb + 32 + quad * 8];
    }

    for (int t = 0; t < NT; ++t) {
      f32x4 acc[2][4];
#pragma unroll
      for (int mt = 0; mt < 2; ++mt)
#pragma unroll
        for (int g = 0; g < 4; ++g) acc[mt][g] = 0.0f;

#pragma unroll
      for (int mt = 0; mt < 2; ++mt) {
        const int m = mt * 16 + l16;
        bf16x8 Ah0 = *(const bf16x8*)&hA[m * 64 + ((quad ^ (m & 7)) << 3)];
        bf16x8 Ah1 = *(const bf16x8*)&hA[m * 64 + (((4 + quad) ^ (m & 7)) << 3)];
#pragma unroll
        for (int g = 0; g < 4; ++g) {
          acc[mt][g] = __builtin_amdgcn_mfma_f32_16x16x32_bf16(Ax0[mt], Bf[g][0], acc[mt][g], 0, 0, 0);
          acc[mt][g] = __builtin_amdgcn_mfma_f32_16x16x32_bf16(Ax1[mt], Bf[g][1], acc[mt][g], 0, 0, 0);
          acc[mt][g] = __builtin_amdgcn_mfma_f32_16x16x32_bf16(Ah0, Bf[g][2], acc[mt][g], 0, 0, 0);
          acc[mt][g] = __builtin_amdgcn_mfma_f32_16x16x32_bf16(Ah1, Bf[g][3], acc[mt][g], 0, 0, 0);
        }
      }

      // prefetch x fragments for t+1 (independent of h / barriers)
      if (t < NT - 1) {
        const int t2 = t + 1;
#pragma unroll
        for (int mt = 0; mt < 2; ++mt) {
          const int m = mt * 16 + l16;
          const int a = mt ? aum1 : aum0;
          const int st = dir ? ((t2 < a) ? (a - 1 - t2) : t2) : t2;
          const size_t rb = ((size_t)(batch0 + m) * NT + st) * NH;
          Ax0[mt] = *(const bf16x8*)&hin[rb + quad * 8];
          Ax1[mt] = *(const bf16x8*)&hin[rb + 32 + quad * 8];
        }
      }

      __syncthreads();   // all hA reads done before epilogue overwrites

#pragma unroll
      for (int mt = 0; mt < 2; ++mt) {
#pragma unroll
        for (int r = 0; r < 4; ++r) {
          const int idx = mt * 4 + r;
          const int bl = mt * 16 + quad * 4 + r;
          float gi = acc[mt][0][r] + bg0;
          float gj = acc[mt][1][r] + bg1;
          float gf = acc[mt][2][r] + bg2;
          float go = acc[mt][3][r] + bg3;
          float nc = sigf(gf + 1.0f) * c_s[idx] + sigf(gi) * tanh_fast(gj);
          float nh = sigf(go) * tanh_fast(nc);
          bool valid = t < aur[idx];
          c_s[idx] = valid ? nc : c_s[idx];
          h_s[idx] = valid ? nh : h_s[idx];
          float outv = valid ? nh : 0.0f;
          int pos = dir ? ((t < aur[idx]) ? (aur[idx] - 1 - t) : t) : t;
          obuf[(dir * 5 + pos) * 2048 + bl * 64 + u] = f2b(outv);
          hA[bl * 64 + (((u >> 3) ^ (bl & 7)) << 3) + (u & 7)] = f2b(h_s[idx]);
        }
      }
      __syncthreads();   // epilogue writes visible before next t GEMM
    }
  }

  // ---- fused final stage: LN over (T,2H), relu, conv dot, masked sum ----
  const float gl  = ln3g[lane],      gh  = ln3g[64 + lane];
  const float bl3 = ln3b[lane],      bh3 = ln3b[64 + lane];
  const float cwl = conv_w[lane],    cwh = conv_w[64 + lane];
  const float cb  = conv_b[0];

  for (int bb = w * 8; bb < w * 8 + 8; ++bb) {
    const int b = batch0 + bb;
    float v0[NT], v1[NT];
#pragma unroll
    for (int p = 0; p < NT; ++p) {
      v0[p] = b2f(obuf[p * 2048 + bb * 64 + lane]);
      v1[p] = b2f(obuf[(5 + p) * 2048 + bb * 64 + lane]);
    }
    float s = 0.0f, q = 0.0f;
#pragma unroll
    for (int p = 0; p < NT; ++p) {
      s += v0[p] + v1[p];
      q += v0[p] * v0[p] + v1[p] * v1[p];
    }
#pragma unroll
    for (int off = 32; off; off >>= 1) {
      s += __shfl_xor(s, off, 64);
      q += __shfl_xor(q, off, 64);
    }
    float m = s * (1.0f / 640.0f);
    float var = q * (1.0f / 640.0f) - m * m;
    float inv = rsqrtf(var + 1e-12f);

    float mk[NT], masksum = 0.0f;
#pragma unroll
    for (int p = 0; p < NT; ++p) {
      mk[p] = mask[b * NT + p];
      masksum += mk[p];
    }
    float local = 0.0f;
#pragma unroll
    for (int p = 0; p < NT; ++p) {
      float xf = fmaxf(0.0f, (v0[p] - m) * inv * gl + bl3);
      float xb = fmaxf(0.0f, (v1[p] - m) * inv * gh + bh3);
      local += mk[p] * (xf * cwl + xb * cwh);
    }
#pragma unroll
    for (int off = 32; off; off >>= 1) local += __shfl_xor(local, off, 64);
    if (lane == 0) out[b] = local + cb * masksum;
  }
}

extern "C" void kernel_launch(void* const* d_in, const int* in_sizes, int n_in,
                              void* d_out, int out_size, void* d_ws, size_t ws_size,
                              hipStream_t stream) {
  const float* ud     = (const float*)d_in[0];
  const float* action = (const float*)d_in[1];
  const float* mask   = (const float*)d_in[2];
  const float* ln0g   = (const float*)d_in[3];
  const float* ln0b   = (const float*)d_in[4];
  const float* W1     = (const float*)d_in[5];
  const float* b1     = (const float*)d_in[6];
  const float* ln1g   = (const float*)d_in[7];
  const float* ln1b   = (const float*)d_in[8];
  const float* W2     = (const float*)d_in[9];
  const float* b2     = (const float*)d_in[10];
  const float* ln2g   = (const float*)d_in[11];
  const float* ln2b   = (const float*)d_in[12];
  const float* fwk    = (const float*)d_in[13];
  const float* fwb    = (const float*)d_in[14];
  const float* bwk    = (const float*)d_in[15];
  const float* bwb    = (const float*)d_in[16];
  const float* ln3g   = (const float*)d_in[17];
  const float* ln3b   = (const float*)d_in[18];
  const float* conv_w = (const float*)d_in[19];
  const float* conv_b = (const float*)d_in[20];
  const int*   au     = (const int*)d_in[21];

  const size_t n_hin = (size_t)NB * NT * NH;   // 20,971,520 elements
  unsigned short* wsu   = (unsigned short*)d_ws;
  unsigned short* hin   = wsu;
  unsigned short* fkT   = hin + n_hin;            // 32768
  unsigned short* bkT   = fkT + 32768;            // 32768
  unsigned short* w1h   = bkT + 32768;            // 8192
  unsigned short* w1l   = w1h + 8192;             // 8192
  unsigned short* w2h   = w1l + 8192;             // 6144
  unsigned short* w2l   = w2h + 6144;             // 6144
  float*          u1    = (float*)(w2l + 6144);   // 64
  float*          vb1   = u1 + 64;                // 64

  float* outf = (float*)d_out;

  k0_prep<<<72, 256, 0, stream>>>(fwk, bwk, W1, W2, ln0g, ln0b, b1,
                                  (unsigned int*)fkT, (unsigned int*)bkT,
                                  w1h, w1l, w2h, w2l, u1, vb1);
  k1_mlp<<<(NB * NT) / 64, 256, 0, stream>>>(ud, action, w1h, w1l, w2h, w2l,
                                             u1, vb1, b2, ln1g, ln1b, ln2g, ln2b,
                                             hin);
  k23_lstm_final<<<NB / 32, 256, 0, stream>>>(hin, fkT, fwb, bkT, bwb, au,
                                              ln3g, ln3b, conv_w, conv_b,
                                              mask, outf);
}